// Round 8
// baseline (1028.741 us; speedup 1.0000x reference)
//
#include <hip/hip_runtime.h>
#include <math.h>

#define NROWS 8192
#define DIM   64
#define KSEL  32
#define NQ    (NROWS - KSEL)   /* 8160 query rows */
#define TPB   256
#define CPT   (NROWS / TPB)    /* 32 candidate slots per thread */

// Kernel A: row norms replicating XLA:CPU (LLVM-vectorized fused reduce):
//   VF=8 lanes, init 0, per-lane FMA chain r[u] = fma(x[8i+u], x[8i+u], r[u]),
//   horizontal shuffle-tree: ((r0+r4)+(r2+r6)) + ((r1+r5)+(r3+r7)).
__global__ void norms_kernel(const float* __restrict__ x, float* __restrict__ sq) {
    int j = blockIdx.x * blockDim.x + threadIdx.x;
    if (j >= NROWS) return;
    const float* xr = x + (size_t)j * DIM;
    float r[8];
#pragma unroll
    for (int u = 0; u < 8; ++u) r[u] = 0.0f;
#pragma unroll
    for (int i = 0; i < DIM; i += 8) {
#pragma unroll
        for (int u = 0; u < 8; ++u)
            r[u] = __fmaf_rn(xr[i + u], xr[i + u], r[u]);
    }
    const float s04 = __fadd_rn(r[0], r[4]);
    const float s26 = __fadd_rn(r[2], r[6]);
    const float s15 = __fadd_rn(r[1], r[5]);
    const float s37 = __fadd_rn(r[3], r[7]);
    sq[j] = __fadd_rn(__fadd_rn(s04, s26), __fadd_rn(s15, s37));
}

// Kernel B: one block per query row r = 32 + blockIdx.x; candidates j < r.
// dot = sequential FMA chain over k=0..63 (Eigen gebp / BLAS microkernel:
// one accumulator per C element).  dist = fl(fl(sqr+sqj) - fl(2*dot)),
// clamped at 0.  Selection: ascending (dist, index), low-index ties.
__global__ __launch_bounds__(TPB)
void knn_kernel(const float* __restrict__ x, const float* __restrict__ sq,
                float* __restrict__ out_d, float* __restrict__ out_i) {
    const int row = blockIdx.x;       // 0..8159
    const int r   = row + KSEL;       // query row index
    const int tid = threadIdx.x;

    __shared__ float dist[NROWS];                 // 32 KB
    __shared__ unsigned long long red[TPB / 64];

    // Query row into registers (64 floats)
    const float4* q4 = reinterpret_cast<const float4*>(x + (size_t)r * DIM);
    float q[DIM];
#pragma unroll
    for (int i = 0; i < DIM / 4; ++i) {
        float4 v = q4[i];
        q[4 * i + 0] = v.x; q[4 * i + 1] = v.y;
        q[4 * i + 2] = v.z; q[4 * i + 3] = v.w;
    }
    const float sqr = sq[r];

    // Phase 1: fp32 distances into LDS (sequential FMA chain, k ascending)
#pragma unroll 2
    for (int t = 0; t < CPT; ++t) {
        const int j = tid + (t << 8);
        float d = INFINITY;
        if (j < r) {
            const float4* xr4 = reinterpret_cast<const float4*>(x + (size_t)j * DIM);
            float4 buf[DIM / 4];
#pragma unroll
            for (int i = 0; i < DIM / 4; ++i) buf[i] = xr4[i];
            float acc = 0.0f;
#pragma unroll
            for (int i = 0; i < DIM / 4; ++i) {
                acc = __fmaf_rn(q[4 * i + 0], buf[i].x, acc);
                acc = __fmaf_rn(q[4 * i + 1], buf[i].y, acc);
                acc = __fmaf_rn(q[4 * i + 2], buf[i].z, acc);
                acc = __fmaf_rn(q[4 * i + 3], buf[i].w, acc);
            }
            d = fmaxf(__fsub_rn(__fadd_rn(sqr, sq[j]), __fmul_rn(2.0f, acc)), 0.0f);
        }
        dist[j] = d;
    }
    __syncthreads();

    // Packed key: (dist_bits<<32) | j.  u64-min => ascending distance,
    // ties -> lower index first (top_k / stable sort semantics).
    unsigned long long pmin = ~0ull;
#pragma unroll
    for (int t = 0; t < CPT; ++t) {
        const int j = tid + (t << 8);
        const unsigned long long p =
            ((unsigned long long)__float_as_uint(dist[j]) << 32) | (unsigned)j;
        pmin = p < pmin ? p : pmin;
    }

    // Phase 2: 32 extract-min iterations
    for (int it = 0; it < KSEL; ++it) {
        unsigned long long v = pmin;
#pragma unroll
        for (int off = 32; off > 0; off >>= 1) {
            const unsigned long long o = __shfl_down(v, off, 64);
            v = o < v ? o : v;
        }
        if ((tid & 63) == 0) red[tid >> 6] = v;
        __syncthreads();
        unsigned long long gmin = red[0];
#pragma unroll
        for (int w = 1; w < TPB / 64; ++w) gmin = red[w] < gmin ? red[w] : gmin;

        const int jstar = (int)(gmin & 0xFFFFFFFFu);
        if (tid == 0) {
            out_d[(size_t)row * KSEL + it] = __uint_as_float((unsigned)(gmin >> 32));
            out_i[(size_t)row * KSEL + it] = (float)jstar;
        }

        // Unique winner (packed value embeds unique j) invalidates and rescans
        if (pmin == gmin) {
            dist[jstar] = INFINITY;
            unsigned long long best = ~0ull;
#pragma unroll
            for (int t = 0; t < CPT; ++t) {
                const int j = tid + (t << 8);
                const unsigned long long p =
                    ((unsigned long long)__float_as_uint(dist[j]) << 32) | (unsigned)j;
                best = p < best ? p : best;
            }
            pmin = best;
        }
        __syncthreads();   // protect red[] before next iteration's write
    }
}

extern "C" void kernel_launch(void* const* d_in, const int* in_sizes, int n_in,
                              void* d_out, int out_size, void* d_ws, size_t ws_size,
                              hipStream_t stream) {
    const float* x = (const float*)d_in[0];    // anchor_x [8192, 64] fp32
    float* sq = (float*)d_ws;                  // 8192 floats of scratch
    float* out_d = (float*)d_out;              // [8160, 32] distances
    float* out_i = out_d + (size_t)NQ * KSEL;  // [8160, 32] indices (as fp32)

    norms_kernel<<<NROWS / TPB, TPB, 0, stream>>>(x, sq);
    knn_kernel<<<NQ, TPB, 0, stream>>>(x, sq, out_d, out_i);
}

// Round 9
// 708.038 us; speedup vs baseline: 1.4529x; 1.4529x over previous
//
#include <hip/hip_runtime.h>
#include <math.h>

#define NROWS 8192
#define DIM   64
#define KSEL  32
#define NQ    (NROWS - KSEL)   /* 8160 query rows */
#define QPB   64               /* queries per block = 1 wave */
#define NQB   128              /* ceil(NQ / QPB) */

// ---------------------------------------------------------------------------
// Kernel A: row norms replicating XLA:CPU (LLVM-vectorized fused reduce):
//   VF=8 lanes, init 0, per-lane FMA chain, horizontal shuffle-tree
//   ((r0+r4)+(r2+r6)) + ((r1+r5)+(r3+r7)).   [validated bit-exact in R8]
// ---------------------------------------------------------------------------
__global__ void norms_kernel(const float* __restrict__ x, float* __restrict__ sq) {
    int j = blockIdx.x * blockDim.x + threadIdx.x;
    if (j >= NROWS) return;
    const float* xr = x + (size_t)j * DIM;
    float r[8];
#pragma unroll
    for (int u = 0; u < 8; ++u) r[u] = 0.0f;
#pragma unroll
    for (int i = 0; i < DIM; i += 8) {
#pragma unroll
        for (int u = 0; u < 8; ++u)
            r[u] = __fmaf_rn(xr[i + u], xr[i + u], r[u]);
    }
    const float s04 = __fadd_rn(r[0], r[4]);
    const float s26 = __fadd_rn(r[2], r[6]);
    const float s15 = __fadd_rn(r[1], r[5]);
    const float s37 = __fadd_rn(r[3], r[7]);
    sq[j] = __fadd_rn(__fadd_rn(s04, s26), __fadd_rn(s15, s37));
}

// ---------------------------------------------------------------------------
// Per-lane 32-entry max-heap of u64 keys in LDS (stride 33 -> conflict-free).
// Keeps the 32 SMALLEST keys seen; root (tau) = current largest kept.
// Precondition: k < tau.
// ---------------------------------------------------------------------------
__device__ inline void heap_insert(unsigned long long* H, unsigned long long k,
                                   unsigned long long& tau) {
    unsigned i = 0;
    while (true) {
        const unsigned l = 2 * i + 1;
        if (l >= KSEL) break;
        const unsigned rr = l + 1;
        unsigned long long cb = H[l];
        unsigned bi = l;
        if (rr < KSEL) {
            const unsigned long long cr = H[rr];
            if (cr > cb) { cb = cr; bi = rr; }
        }
        if (cb > k) {
            H[i] = cb;
            if (i == 0) tau = cb;
            i = bi;
        } else break;
    }
    H[i] = k;
    if (i == 0) tau = k;
}

// ---------------------------------------------------------------------------
// Kernel B: distance + streaming per-lane top-32.
// Grid (NQB, maxc).  Block = 1 wave.  Lane owns query r = 32 + 64*qb + lane.
// Candidate index j is WAVE-UNIFORM -> candidate row & sq[j] are broadcast
// (scalar) loads.  Dot = bit-exact sequential FMA chain, d = 0..63.
// Partial top-32 per (query, chunk) written to scratch.
// ---------------------------------------------------------------------------
__global__ __launch_bounds__(QPB)
void dist_kernel(const float* __restrict__ x, const float* __restrict__ sq,
                 unsigned long long* __restrict__ partial,
                 int chunk, int maxc) {
    const int qb   = blockIdx.x;
    const int c    = blockIdx.y;
    const int lane = threadIdx.x;

    const int r_hi = min(32 + (qb + 1) * QPB, NROWS);   // exclusive cap
    const int jbeg = c * chunk;
    if (jbeg >= r_hi) return;                            // no lane needs this chunk
    const int jend = min(jbeg + chunk, r_hi);            // both even

    const int  r_raw = 32 + qb * QPB + lane;
    const bool vq    = (r_raw < NROWS);
    const int  r     = vq ? r_raw : 0;                   // r=0 => never accepts
    const int  qrow  = vq ? r_raw : 0;

    __shared__ unsigned long long heap[QPB * 33];
    unsigned long long* H = heap + lane * 33;
#pragma unroll
    for (int s = 0; s < KSEL; ++s) H[s] = ~0ull;
    unsigned long long tau = ~0ull;

    // Per-lane query row into registers
    float q[DIM];
    const float4* q4 = reinterpret_cast<const float4*>(x + (size_t)qrow * DIM);
#pragma unroll
    for (int i = 0; i < DIM / 4; ++i) {
        float4 v = q4[i];
        q[4 * i + 0] = v.x; q[4 * i + 1] = v.y;
        q[4 * i + 2] = v.z; q[4 * i + 3] = v.w;
    }
    const float sqr = sq[qrow];

    // Candidate stream, 2 per step for FMA ILP (jbeg/jend even)
    for (int j0 = jbeg; j0 < jend; j0 += 2) {
        const float* c0 = x + (size_t)j0 * DIM;
        const float* c1 = c0 + DIM;
        float a0 = 0.0f, a1 = 0.0f;
#pragma unroll
        for (int d = 0; d < DIM; ++d) {
            a0 = __fmaf_rn(q[d], c0[d], a0);
            a1 = __fmaf_rn(q[d], c1[d], a1);
        }
        const float sq0 = sq[j0], sq1 = sq[j0 + 1];
        const float d0 = fmaxf(__fsub_rn(__fadd_rn(sqr, sq0), __fmul_rn(2.0f, a0)), 0.0f);
        const float d1 = fmaxf(__fsub_rn(__fadd_rn(sqr, sq1), __fmul_rn(2.0f, a1)), 0.0f);
        const unsigned long long k0 =
            ((unsigned long long)__float_as_uint(d0) << 32) | (unsigned)j0;
        const unsigned long long k1 =
            ((unsigned long long)__float_as_uint(d1) << 32) | (unsigned)(j0 + 1);
        if (j0 < r && k0 < tau)     heap_insert(H, k0, tau);
        if (j0 + 1 < r && k1 < tau) heap_insert(H, k1, tau);
    }

    // Write partial top-32 for (query, chunk)
    if (vq) {
        const int qi = r_raw - KSEL;
        unsigned long long* dst = partial + ((size_t)qi * maxc + c) * KSEL;
#pragma unroll
        for (int s = 0; s < KSEL; ++s) dst[s] = H[s];
    }
}

// ---------------------------------------------------------------------------
// Kernel C: merge per-chunk partials -> exact global top-32 per query.
// One wave per query.  u64-min keys = ascending (dist, index), low-index ties.
// ---------------------------------------------------------------------------
__global__ __launch_bounds__(64)
void merge_kernel(const unsigned long long* __restrict__ partial,
                  int chunk, int maxc,
                  float* __restrict__ out_d, float* __restrict__ out_i) {
    const int qi   = blockIdx.x;     // 0..8159
    const int r    = qi + KSEL;
    const int lane = threadIdx.x;
    const int nc   = (r + chunk - 1) / chunk;
    const int ne   = nc * KSEL;      // <= 512

    const unsigned long long* src = partial + (size_t)qi * maxc * KSEL;
    unsigned long long e[8];
#pragma unroll
    for (int s = 0; s < 8; ++s) {
        const int idx = s * 64 + lane;
        e[s] = (idx < ne) ? src[idx] : ~0ull;
    }
    unsigned long long pmin = ~0ull;
#pragma unroll
    for (int s = 0; s < 8; ++s) pmin = e[s] < pmin ? e[s] : pmin;

    for (int it = 0; it < KSEL; ++it) {
        unsigned long long v = pmin;
#pragma unroll
        for (int off = 32; off > 0; off >>= 1) {
            const unsigned long long o = __shfl_down(v, off, 64);
            v = o < v ? o : v;
        }
        const unsigned long long g = __shfl(v, 0, 64);

        if (lane == 0) {
            out_d[(size_t)qi * KSEL + it] = __uint_as_float((unsigned)(g >> 32));
            out_i[(size_t)qi * KSEL + it] = (float)(unsigned)(g & 0xFFFFFFFFu);
        }
        if (pmin == g) {   // unique winner (keys embed unique j)
#pragma unroll
            for (int s = 0; s < 8; ++s) if (e[s] == g) e[s] = ~0ull;
            pmin = ~0ull;
#pragma unroll
            for (int s = 0; s < 8; ++s) pmin = e[s] < pmin ? e[s] : pmin;
        }
    }
}

extern "C" void kernel_launch(void* const* d_in, const int* in_sizes, int n_in,
                              void* d_out, int out_size, void* d_ws, size_t ws_size,
                              hipStream_t stream) {
    const float* x = (const float*)d_in[0];    // anchor_x [8192, 64] fp32
    float* sq = (float*)d_ws;                  // 8192 floats
    unsigned long long* partial =
        (unsigned long long*)((char*)d_ws + 32768);
    float* out_d = (float*)d_out;              // [8160, 32] distances
    float* out_i = out_d + (size_t)NQ * KSEL;  // [8160, 32] indices (as fp32)

    // Pick the smallest chunk (most parallelism) whose scratch fits ws_size.
    int chunk = NROWS;
    for (int c = 512; c <= NROWS; c <<= 1) {
        const size_t need = 32768 + (size_t)NQ * (NROWS / c) * KSEL * 8;
        if (need <= ws_size) { chunk = c; break; }
    }
    const int maxc = NROWS / chunk;

    norms_kernel<<<NROWS / 256, 256, 0, stream>>>(x, sq);
    dim3 grid(NQB, maxc);
    dist_kernel<<<grid, QPB, 0, stream>>>(x, sq, partial, chunk, maxc);
    merge_kernel<<<NQ, 64, 0, stream>>>(partial, chunk, maxc, out_d, out_i);
}